// Round 2
// baseline (221.614 us; speedup 1.0000x reference)
//
#include <hip/hip_runtime.h>

// Problem dims (hard-coded in reference)
#define DD   768
#define NN   512
#define MM   512

// ---- fast-math helpers -----------------------------------------------------
#if defined(__has_builtin)
  #if __has_builtin(__builtin_amdgcn_exp2f)
    #define HAVE_EXP2 1
  #endif
  #if __has_builtin(__builtin_amdgcn_rcpf)
    #define HAVE_RCP 1
  #endif
#endif

#ifdef HAVE_EXP2
  // fexp(x) computes 2^x; caller pre-scales by 2*log2(e) so fexp(PRE_K*v) = e^{2v}
  __device__ __forceinline__ float fexp(float x) { return __builtin_amdgcn_exp2f(x); }
  #define PRE_K 2.88539008177792681472f   // 2*log2(e)
#else
  __device__ __forceinline__ float fexp(float x) { return __expf(x); }
  #define PRE_K 2.0f
#endif

__device__ __forceinline__ float frcp(float x) {
#ifdef HAVE_RCP
  return __builtin_amdgcn_rcpf(x);
#else
  return 1.0f / x;
#endif
}

// tanh(x) = 1 - 2/(1 + e^{2x}); saturates correctly via exp2->inf/0 + rcp.
__device__ __forceinline__ float fast_tanh(float x) {
  float e = fexp(PRE_K * x);
  return 1.0f - 2.0f * frcp(e + 1.0f);
}

// ---- generic 64x64 fp32 GEMM tile (256 thr, 4x4/thread, BK=16, K-range) ----
// Out[i,j] += scale * sum_{k in [k0,k1)} X[i,k] * (transB ? W[j,k] : W[k,j])
// Accumulated with HW fp32 atomics (Out must be pre-zeroed).
#define GLD 68   // LDS leading dim pad: 64->68 keeps float4 align, 2-way banks

__device__ __forceinline__ void gemm_tile(
    const float* __restrict__ X, const float* __restrict__ W,
    float* __restrict__ Out, int ldo,
    int i0, int j0, int ldx, int ldw,
    int k0, int k1, bool transB, float scale)
{
  __shared__ float Xs[16][GLD];   // [k][row]
  __shared__ float Ws[16][GLD];   // [k][col]
  const int tid = threadIdx.x;
  const int tx = tid & 15;       // col group
  const int ty = tid >> 4;       // row group
  float acc[4][4] = {};

  for (int k = k0; k < k1; k += 16) {
    // stage X tile (64 rows x 16 k), one float4 per thread, store transposed
    {
      const int row = tid >> 2;
      const int kq  = (tid & 3) << 2;
      const float4 v = *(const float4*)&X[(i0 + row) * ldx + k + kq];
      Xs[kq + 0][row] = v.x; Xs[kq + 1][row] = v.y;
      Xs[kq + 2][row] = v.z; Xs[kq + 3][row] = v.w;
    }
    if (!transB) {
      const int r  = tid >> 4;           // k index 0..15
      const int cq = (tid & 15) << 2;    // col 0..63 step 4
      *(float4*)&Ws[r][cq] = *(const float4*)&W[(k + r) * ldw + j0 + cq];
    } else {
      const int c  = tid >> 2;           // col 0..63
      const int kq = (tid & 3) << 2;
      const float4 v = *(const float4*)&W[(j0 + c) * ldw + k + kq];
      Ws[kq + 0][c] = v.x; Ws[kq + 1][c] = v.y;
      Ws[kq + 2][c] = v.z; Ws[kq + 3][c] = v.w;
    }
    __syncthreads();
    #pragma unroll
    for (int kk = 0; kk < 16; ++kk) {
      const float4 xv = *(const float4*)&Xs[kk][ty << 2];
      const float4 wv = *(const float4*)&Ws[kk][tx << 2];
      const float xa[4] = {xv.x, xv.y, xv.z, xv.w};
      const float wa[4] = {wv.x, wv.y, wv.z, wv.w};
      #pragma unroll
      for (int r = 0; r < 4; ++r)
        #pragma unroll
        for (int c = 0; c < 4; ++c)
          acc[r][c] = fmaf(xa[r], wa[c], acc[r][c]);
    }
    __syncthreads();
  }

  #pragma unroll
  for (int r = 0; r < 4; ++r)
    #pragma unroll
    for (int c = 0; c < 4; ++c)
      unsafeAtomicAdd(&Out[(i0 + (ty << 2) + r) * ldo + j0 + (tx << 2) + c],
                      acc[r][c] * scale);
}

// z = gemm*4 + ksplit.  gemm 0: A = text@W1 ; 1: kw2t = PRE_K*(text@W2) ;
// 2: kw3v = PRE_K*(visual@W3^T).  K split 4 ways (192 each) for occupancy.
__global__ __launch_bounds__(256) void gemm3_kernel(
    const float* __restrict__ text, const float* __restrict__ visual,
    const float* __restrict__ W1, const float* __restrict__ W2,
    const float* __restrict__ W3,
    float* __restrict__ A, float* __restrict__ kw2t, float* __restrict__ kw3v)
{
  const int i0 = blockIdx.y * 64;
  const int j0 = blockIdx.x * 64;
  const int g  = blockIdx.z >> 2;
  const int ks = blockIdx.z & 3;
  const int k0 = ks * (DD / 4), k1 = k0 + DD / 4;
  if (g == 0)
    gemm_tile(text,   W1, A,    DD, i0, j0, DD, DD, k0, k1, false, 1.0f);
  else if (g == 1)
    gemm_tile(text,   W2, kw2t, DD, i0, j0, DD, DD, k0, k1, false, PRE_K);
  else
    gemm_tile(visual, W3, kw3v, DD, i0, j0, DD, DD, k0, k1, true,  PRE_K);
}

// Craw = A @ visual^T, K split 8 ways (96 each) -> 512 blocks
__global__ __launch_bounds__(256) void cgemm_kernel(
    const float* __restrict__ A, const float* __restrict__ visual,
    float* __restrict__ C)
{
  const int i0 = blockIdx.y * 64;
  const int j0 = blockIdx.x * 64;
  const int k0 = blockIdx.z * (DD / 8), k1 = k0 + DD / 8;
  gemm_tile(A, visual, C, MM, i0, j0, DD, DD, k0, k1, true, 1.0f);
}

// T[n] = sum_d text[n,d]  (for score = T[n] - 2*sum text*r identity)
__global__ __launch_bounds__(64) void tsum_kernel(
    const float* __restrict__ text, float* __restrict__ T)
{
  const int n = blockIdx.x;
  const int lane = threadIdx.x;
  float s = 0.f;
  #pragma unroll
  for (int i = 0; i < DD / 64; ++i) s += text[n * DD + lane + i * 64];
  #pragma unroll
  for (int off = 32; off; off >>= 1) s += __shfl_down(s, off);
  if (lane == 0) T[n] = s;
}

// ---- main fused kernel -----------------------------------------------------
// score[n,m] = T[n] - 2 * sum_d text[n,d] * rcp(1 + exp2(kw2t[n,d] + kw3v[m,d]*C[n,m]))
#define DCH 128          // d-chunk staged per iteration
#define LDW 132          // LDS row stride (pad 128 -> 132: float4-aligned, 2-way max)

__global__ __launch_bounds__(256) void main_kernel(
    const float* __restrict__ text, const float* __restrict__ kw2t,
    const float* __restrict__ kw3v, const float* __restrict__ C,
    const float* __restrict__ T,    float* __restrict__ out)
{
  __shared__ float ts[16][LDW];
  __shared__ float w2s[16][LDW];
  __shared__ float w3s[16][LDW];

  const int tid = threadIdx.x;
  const int nl = tid >> 4;            // local n 0..15
  const int ml = tid & 15;            // local m 0..15
  const int n0 = blockIdx.y * 16;
  const int m0 = blockIdx.x * 16;
  const int n = n0 + nl, m = m0 + ml;

  const float cval = fast_tanh(C[n * MM + m]);

  float a0 = 0.f, a1 = 0.f, a2 = 0.f, a3 = 0.f;

  for (int d0 = 0; d0 < DD; d0 += DCH) {
    #pragma unroll
    for (int t = 0; t < 2; ++t) {
      const int q   = tid + t * 256;      // 0..511 (16 rows x 32 float4)
      const int row = q >> 5;
      const int c4  = (q & 31) << 2;
      const float4 tv = *(const float4*)&text[(n0 + row) * DD + d0 + c4];
      const float4 av = *(const float4*)&kw2t[(n0 + row) * DD + d0 + c4];
      const float4 bv = *(const float4*)&kw3v[(m0 + row) * DD + d0 + c4];
      *(float4*)&ts[row][c4]  = tv;
      *(float4*)&w2s[row][c4] = av;
      *(float4*)&w3s[row][c4] = bv;
    }
    __syncthreads();

    #pragma unroll 4
    for (int j = 0; j < DCH; j += 4) {
      const float4 tv = *(const float4*)&ts[nl][j];
      const float4 w2 = *(const float4*)&w2s[nl][j];
      const float4 w3 = *(const float4*)&w3s[ml][j];
      const float p0 = fmaf(w3.x, cval, w2.x);
      const float p1 = fmaf(w3.y, cval, w2.y);
      const float p2 = fmaf(w3.z, cval, w2.z);
      const float p3 = fmaf(w3.w, cval, w2.w);
      a0 = fmaf(tv.x, frcp(fexp(p0) + 1.0f), a0);
      a1 = fmaf(tv.y, frcp(fexp(p1) + 1.0f), a1);
      a2 = fmaf(tv.z, frcp(fexp(p2) + 1.0f), a2);
      a3 = fmaf(tv.w, frcp(fexp(p3) + 1.0f), a3);
    }
    __syncthreads();
  }

  const float acc = (a0 + a1) + (a2 + a3);
  out[n * MM + m] = T[n] - 2.0f * acc;
}

// ---- launcher --------------------------------------------------------------
extern "C" void kernel_launch(void* const* d_in, const int* in_sizes, int n_in,
                              void* d_out, int out_size, void* d_ws, size_t ws_size,
                              hipStream_t stream) {
  const float* text   = (const float*)d_in[0];
  const float* visual = (const float*)d_in[1];
  const float* W1     = (const float*)d_in[2];
  const float* W2     = (const float*)d_in[3];
  const float* W3     = (const float*)d_in[4];
  float* out = (float*)d_out;

  float* ws   = (float*)d_ws;
  float* A    = ws;                         // 512*768
  float* kw2t = ws + NN * DD;               // 512*768
  float* kw3v = ws + 2 * NN * DD;           // 512*768
  float* C    = ws + 3 * NN * DD;           // 512*512
  float* T    = C + NN * MM;                // 512

  // zero the atomic accumulation buffers (A, kw2t, kw3v, C — contiguous)
  hipMemsetAsync(ws, 0, (size_t)(3 * NN * DD + NN * MM) * sizeof(float), stream);

  hipLaunchKernelGGL(tsum_kernel, dim3(NN), dim3(64), 0, stream, text, T);
  hipLaunchKernelGGL(gemm3_kernel, dim3(DD / 64, NN / 64, 12), dim3(256), 0, stream,
                     text, visual, W1, W2, W3, A, kw2t, kw3v);
  hipLaunchKernelGGL(cgemm_kernel, dim3(MM / 64, NN / 64, 8), dim3(256), 0, stream,
                     A, visual, C);
  hipLaunchKernelGGL(main_kernel, dim3(MM / 16, NN / 16), dim3(256), 0, stream,
                     text, kw2t, kw3v, C, T, out);
}

// Round 3
// 161.493 us; speedup vs baseline: 1.3723x; 1.3723x over previous
//
#include <hip/hip_runtime.h>

// Problem dims (hard-coded in reference)
#define DD   768
#define NN   512
#define MM   512

#define PRE_K 2.88539008177792681472f   // 2*log2(e)

__device__ __forceinline__ float fexp(float x) { return __builtin_amdgcn_exp2f(x); }
__device__ __forceinline__ float frcp(float x) { return __builtin_amdgcn_rcpf(x); }
// tanh(x) = 1 - 2/(1 + e^{2x}); saturates correctly via exp2->inf/0 + rcp.
__device__ __forceinline__ float fast_tanh(float x) {
  return 1.0f - 2.0f * frcp(fexp(PRE_K * x) + 1.0f);
}

// ---- 64x64 fp32 GEMM tile, double-buffered LDS, K-range, plain stores ------
// Out[i,j] = sum_{k in range} X[i,k] * (TRANSB ? W[j,k] : W[k,j])
// NO atomics: each K-split writes its own partial buffer (R2 lesson: device
// atomics flush to HBM on gfx950 -> 75MB write traffic).
#define GLD 68   // LDS leading dim pad: float4-aligned, <=2-way banks (free)

template <bool TRANSB>
__device__ __forceinline__ void gemm_tile_db(
    const float* __restrict__ X, const float* __restrict__ W,
    float* __restrict__ Out, int ldo,
    int i0, int j0, int ldx, int ldw, int k0, int ksteps)
{
  __shared__ float Xs[2][16][GLD];   // [buf][k][row]
  __shared__ float Ws[2][16][GLD];   // [buf][k][col]
  const int tid  = threadIdx.x;
  const int xrow = tid >> 2;            // 0..63
  const int xkq  = (tid & 3) << 2;      // 0,4,8,12
  const int tx   = tid & 15;            // col group
  const int ty   = tid >> 4;            // row group

  const float* xp = &X[(i0 + xrow) * ldx + k0 + xkq];
  const float* wp = TRANSB
      ? &W[(j0 + (tid >> 2)) * ldw + k0 + ((tid & 3) << 2)]
      : &W[(k0 + (tid >> 4)) * ldw + j0 + ((tid & 15) << 2)];

  // prefetch step 0 into registers
  float4 xv = *(const float4*)xp;
  float4 wv = *(const float4*)wp;

  float acc[4][4] = {};
  int p = 0;

  // stage step 0 into buffer 0
  Xs[0][xkq + 0][xrow] = xv.x; Xs[0][xkq + 1][xrow] = xv.y;
  Xs[0][xkq + 2][xrow] = xv.z; Xs[0][xkq + 3][xrow] = xv.w;
  if (TRANSB) {
    const int c = tid >> 2, kq = (tid & 3) << 2;
    Ws[0][kq + 0][c] = wv.x; Ws[0][kq + 1][c] = wv.y;
    Ws[0][kq + 2][c] = wv.z; Ws[0][kq + 3][c] = wv.w;
  } else {
    *(float4*)&Ws[0][tid >> 4][(tid & 15) << 2] = wv;
  }
  __syncthreads();

  for (int s = 0; s < ksteps; ++s) {
    const bool more = (s + 1 < ksteps);
    if (more) {
      // issue next step's global loads early; compute below hides latency
      xv = *(const float4*)(xp + (s + 1) * 16);
      wv = TRANSB ? *(const float4*)(wp + (s + 1) * 16)
                  : *(const float4*)(wp + (size_t)(s + 1) * 16 * ldw);
    }
    #pragma unroll
    for (int kk = 0; kk < 16; ++kk) {
      const float4 xr = *(const float4*)&Xs[p][kk][ty << 2];
      const float4 wr = *(const float4*)&Ws[p][kk][tx << 2];
      const float xa[4] = {xr.x, xr.y, xr.z, xr.w};
      const float wa[4] = {wr.x, wr.y, wr.z, wr.w};
      #pragma unroll
      for (int r = 0; r < 4; ++r)
        #pragma unroll
        for (int c = 0; c < 4; ++c)
          acc[r][c] = fmaf(xa[r], wa[c], acc[r][c]);
    }
    if (more) {
      const int q = p ^ 1;
      Xs[q][xkq + 0][xrow] = xv.x; Xs[q][xkq + 1][xrow] = xv.y;
      Xs[q][xkq + 2][xrow] = xv.z; Xs[q][xkq + 3][xrow] = xv.w;
      if (TRANSB) {
        const int c = tid >> 2, kq = (tid & 3) << 2;
        Ws[q][kq + 0][c] = wv.x; Ws[q][kq + 1][c] = wv.y;
        Ws[q][kq + 2][c] = wv.z; Ws[q][kq + 3][c] = wv.w;
      } else {
        *(float4*)&Ws[q][tid >> 4][(tid & 15) << 2] = wv;
      }
    }
    __syncthreads();
    p ^= 1;
  }

  #pragma unroll
  for (int r = 0; r < 4; ++r) {
    float4 o;
    o.x = acc[r][0]; o.y = acc[r][1]; o.z = acc[r][2]; o.w = acc[r][3];
    *(float4*)&Out[(i0 + (ty << 2) + r) * ldo + j0 + (tx << 2)] = o;
  }
}

// z = g*2 + ks. g 0: text@W1 ; 1: text@W2 ; 2: visual@W3^T.  K split 2 (384).
// Partials P[z] (NN*DD each); reduce3 combines + applies PRE_K scaling.
__global__ __launch_bounds__(256) void gemm3_kernel(
    const float* __restrict__ text, const float* __restrict__ visual,
    const float* __restrict__ W1, const float* __restrict__ W2,
    const float* __restrict__ W3, float* __restrict__ P)
{
  const int i0 = blockIdx.y * 64;
  const int j0 = blockIdx.x * 64;
  const int z  = blockIdx.z;
  const int g  = z >> 1;
  const int k0 = (z & 1) * (DD / 2);
  float* Out = P + (size_t)z * NN * DD;
  if (g == 0)
    gemm_tile_db<false>(text,   W1, Out, DD, i0, j0, DD, DD, k0, 24);
  else if (g == 1)
    gemm_tile_db<false>(text,   W2, Out, DD, i0, j0, DD, DD, k0, 24);
  else
    gemm_tile_db<true>(visual,  W3, Out, DD, i0, j0, DD, DD, k0, 24);
}

// A = P0+P1 ; kw2t = PRE_K*(P2+P3) ; kw3v = PRE_K*(P4+P5)
__global__ __launch_bounds__(256) void reduce3_kernel(
    const float* __restrict__ P, float* __restrict__ A,
    float* __restrict__ kw2t, float* __restrict__ kw3v)
{
  const size_t i = ((size_t)blockIdx.x * 256 + threadIdx.x) * 4;  // float idx
  const size_t S = (size_t)NN * DD;
  float4 a0 = *(const float4*)&P[i];
  float4 a1 = *(const float4*)&P[S + i];
  float4 b0 = *(const float4*)&P[2 * S + i];
  float4 b1 = *(const float4*)&P[3 * S + i];
  float4 c0 = *(const float4*)&P[4 * S + i];
  float4 c1 = *(const float4*)&P[5 * S + i];
  float4 o;
  o.x = a0.x + a1.x; o.y = a0.y + a1.y; o.z = a0.z + a1.z; o.w = a0.w + a1.w;
  *(float4*)&A[i] = o;
  o.x = PRE_K * (b0.x + b1.x); o.y = PRE_K * (b0.y + b1.y);
  o.z = PRE_K * (b0.z + b1.z); o.w = PRE_K * (b0.w + b1.w);
  *(float4*)&kw2t[i] = o;
  o.x = PRE_K * (c0.x + c1.x); o.y = PRE_K * (c0.y + c1.y);
  o.z = PRE_K * (c0.z + c1.z); o.w = PRE_K * (c0.w + c1.w);
  *(float4*)&kw3v[i] = o;
}

// Craw partials: Q[z] = A @ visual^T over K range z*96..+96  (8-way split)
__global__ __launch_bounds__(256) void cgemm_kernel(
    const float* __restrict__ A, const float* __restrict__ visual,
    float* __restrict__ Q)
{
  const int i0 = blockIdx.y * 64;
  const int j0 = blockIdx.x * 64;
  const int z  = blockIdx.z;
  gemm_tile_db<true>(A, visual, Q + (size_t)z * NN * MM, MM,
                     i0, j0, DD, DD, z * (DD / 8), 6);
}

// C = tanh(sum_z Q[z])  (tanh folded here; main reads post-tanh C)
__global__ __launch_bounds__(256) void reducec_kernel(
    const float* __restrict__ Q, float* __restrict__ C)
{
  const size_t i = ((size_t)blockIdx.x * 256 + threadIdx.x) * 4;
  const size_t S = (size_t)NN * MM;
  float4 s = *(const float4*)&Q[i];
  #pragma unroll
  for (int z = 1; z < 8; ++z) {
    const float4 q = *(const float4*)&Q[z * S + i];
    s.x += q.x; s.y += q.y; s.z += q.z; s.w += q.w;
  }
  float4 o;
  o.x = fast_tanh(s.x); o.y = fast_tanh(s.y);
  o.z = fast_tanh(s.z); o.w = fast_tanh(s.w);
  *(float4*)&C[i] = o;
}

// T[n] = sum_d text[n,d]  (for score = T[n] - 2*sum text*r identity)
__global__ __launch_bounds__(64) void tsum_kernel(
    const float* __restrict__ text, float* __restrict__ T)
{
  const int n = blockIdx.x;
  const int lane = threadIdx.x;
  float s = 0.f;
  #pragma unroll
  for (int i = 0; i < DD / 64; ++i) s += text[n * DD + lane + i * 64];
  #pragma unroll
  for (int off = 32; off; off >>= 1) s += __shfl_down(s, off);
  if (lane == 0) T[n] = s;
}

// ---- main fused kernel -----------------------------------------------------
// score[n,m] = T[n] - 2 * sum_d text[n,d] * rcp(1 + exp2(kw2t[n,d] + kw3v[m,d]*C[n,m]))
#define DCH 128          // d-chunk staged per iteration
#define LDW 132          // LDS row stride (pad 128 -> 132: float4-aligned, 2-way max)

__global__ __launch_bounds__(256) void main_kernel(
    const float* __restrict__ text, const float* __restrict__ kw2t,
    const float* __restrict__ kw3v, const float* __restrict__ C,
    const float* __restrict__ T,    float* __restrict__ out)
{
  __shared__ float ts[16][LDW];
  __shared__ float w2s[16][LDW];
  __shared__ float w3s[16][LDW];

  const int tid = threadIdx.x;
  const int nl = tid >> 4;            // local n 0..15
  const int ml = tid & 15;            // local m 0..15
  const int n0 = blockIdx.y * 16;
  const int m0 = blockIdx.x * 16;
  const int n = n0 + nl, m = m0 + ml;

  const float cval = C[n * MM + m];   // already tanh'd by reducec

  float a0 = 0.f, a1 = 0.f, a2 = 0.f, a3 = 0.f;

  for (int d0 = 0; d0 < DD; d0 += DCH) {
    #pragma unroll
    for (int t = 0; t < 2; ++t) {
      const int q   = tid + t * 256;      // 0..511 (16 rows x 32 float4)
      const int row = q >> 5;
      const int c4  = (q & 31) << 2;
      const float4 tv = *(const float4*)&text[(n0 + row) * DD + d0 + c4];
      const float4 av = *(const float4*)&kw2t[(n0 + row) * DD + d0 + c4];
      const float4 bv = *(const float4*)&kw3v[(m0 + row) * DD + d0 + c4];
      *(float4*)&ts[row][c4]  = tv;
      *(float4*)&w2s[row][c4] = av;
      *(float4*)&w3s[row][c4] = bv;
    }
    __syncthreads();

    #pragma unroll 4
    for (int j = 0; j < DCH; j += 4) {
      const float4 tv = *(const float4*)&ts[nl][j];
      const float4 w2 = *(const float4*)&w2s[nl][j];
      const float4 w3 = *(const float4*)&w3s[ml][j];
      const float p0 = fmaf(w3.x, cval, w2.x);
      const float p1 = fmaf(w3.y, cval, w2.y);
      const float p2 = fmaf(w3.z, cval, w2.z);
      const float p3 = fmaf(w3.w, cval, w2.w);
      a0 = fmaf(tv.x, frcp(fexp(p0) + 1.0f), a0);
      a1 = fmaf(tv.y, frcp(fexp(p1) + 1.0f), a1);
      a2 = fmaf(tv.z, frcp(fexp(p2) + 1.0f), a2);
      a3 = fmaf(tv.w, frcp(fexp(p3) + 1.0f), a3);
    }
    __syncthreads();
  }

  const float acc = (a0 + a1) + (a2 + a3);
  out[n * MM + m] = T[n] - 2.0f * acc;
}

// ---- launcher --------------------------------------------------------------
extern "C" void kernel_launch(void* const* d_in, const int* in_sizes, int n_in,
                              void* d_out, int out_size, void* d_ws, size_t ws_size,
                              hipStream_t stream) {
  const float* text   = (const float*)d_in[0];
  const float* visual = (const float*)d_in[1];
  const float* W1     = (const float*)d_in[2];
  const float* W2     = (const float*)d_in[3];
  const float* W3     = (const float*)d_in[4];
  float* out = (float*)d_out;

  float* ws = (float*)d_ws;
  // Region P: 6*NN*DD floats for gemm3 partials; REUSED afterwards for the
  // 8*NN*MM cgemm partials (8*262144 = 2097152 <= 2359296). Safe because
  // reduce3 fully consumes P before cgemm writes Q.
  float* P    = ws;
  float* Q    = ws;
  float* A    = ws + 6 * NN * DD;           // 512*768
  float* kw2t = A + NN * DD;
  float* kw3v = kw2t + NN * DD;
  float* C    = kw3v + NN * DD;             // 512*512
  float* T    = C + NN * MM;                // 512

  hipLaunchKernelGGL(tsum_kernel, dim3(NN), dim3(64), 0, stream, text, T);
  hipLaunchKernelGGL(gemm3_kernel, dim3(DD / 64, NN / 64, 6), dim3(256), 0, stream,
                     text, visual, W1, W2, W3, P);
  hipLaunchKernelGGL(reduce3_kernel, dim3(NN * DD / 1024), dim3(256), 0, stream,
                     P, A, kw2t, kw3v);
  hipLaunchKernelGGL(cgemm_kernel, dim3(MM / 64, NN / 64, 8), dim3(256), 0, stream,
                     A, visual, Q);
  hipLaunchKernelGGL(reducec_kernel, dim3(NN * MM / 1024), dim3(256), 0, stream,
                     Q, C);
  hipLaunchKernelGGL(main_kernel, dim3(MM / 16, NN / 16), dim3(256), 0, stream,
                     text, kw2t, kw3v, C, T, out);
}